// Round 12
// baseline (647.469 us; speedup 1.0000x reference)
//
#include <hip/hip_runtime.h>

typedef __attribute__((ext_vector_type(8))) __bf16 bf16x8;
typedef __attribute__((ext_vector_type(4))) float f32x4;
typedef unsigned short u16;
typedef unsigned int u32;

__device__ __forceinline__ u16 f2bf(float x){
  u32 u = __float_as_uint(x);
  return (u16)((u + 0x7fffu + ((u >> 16) & 1u)) >> 16);
}
__device__ __forceinline__ u32 pkbf(float lo, float hi){
  u32 r; asm("v_cvt_pk_bf16_f32 %0, %1, %2" : "=v"(r) : "v"(lo), "v"(hi)); return r;
}

union FragU { uint4 u4; bf16x8 bf; };

__device__ __forceinline__ bf16x8 lds_frag(const unsigned char* smem, int off, int row, int strideB, int kElem){
  int byte = (row * strideB + kElem * 2) ^ ((row & 7) << 4);
  FragU f; f.u4 = *reinterpret_cast<const uint4*>(smem + off + byte);
  return f.bf;
}

typedef __attribute__((address_space(3))) unsigned char lds_u8;
typedef __attribute__((address_space(1))) const unsigned char g_u8;
__device__ __forceinline__ void glds16(const void* g, void* l){
  __builtin_amdgcn_global_load_lds((g_u8*)g, (lds_u8*)l, 16, 0, 0);
}

__global__ void prep_weights(const float* __restrict__ wq, const float* __restrict__ wp,
                             u16* __restrict__ wqb, u16* __restrict__ wpb){
  int i = blockIdx.x * 256 + threadIdx.x;
  wqb[i] = f2bf(wq[i]);              // grid sized exactly for 442368
  if (i < 147456) wpb[i] = f2bf(wp[i]);
}

// x f32 -> bf16, linear [147456][384]
__global__ void prep_x(const float* __restrict__ x, u16* __restrict__ xb){
  size_t i = ((size_t)blockIdx.x * 256 + threadIdx.x) * 8;
  float4 f0 = *reinterpret_cast<const float4*>(x + i);
  float4 f1 = *reinterpret_cast<const float4*>(x + i + 4);
  uint4 q;
  q.x = pkbf(f0.x, f0.y); q.y = pkbf(f0.z, f0.w);
  q.z = pkbf(f1.x, f1.y); q.w = pkbf(f1.z, f1.w);
  *reinterpret_cast<uint4*>(xb + i) = q;
}

// ======================================================================
// K2 v12: WINDOW-PAIR qkv GEMM. One (window pair g2, sec) per block,
// 512 thr = 8 waves: wh = window half (M=2x80), wc = 96-col quarter.
// B panel [384][64] staged per k-tile now amortized over 2x the M-work
// (stage ratio 1.7x better than r11). A gathered per-token via glds16.
// Outputs identical to r11: q/k window-head-tiled in out; v transposed
// (two-pass in-LDS) to vws[g][h][64ch][80tok], toks 72..79 zeroed.
// ======================================================================
#define W2A  0          // A [2][80][64] bf16 swz : 20480
#define W2B  20480      // B [384][64] bf16 swz : 49152 -> 69632
#define W2VT 0          // v transpose [384ch][80tok] (aliases A+B) : 61440
#define W2TC 69632      // 288 f32
#define W2TS 70784      // -> 71936
__launch_bounds__(512, 2)
__global__ void qkv_win2(const u16* __restrict__ xb, const u16* __restrict__ wqb,
                         const float* __restrict__ bq, float* __restrict__ out,
                         u16* __restrict__ vws)
{
  __shared__ __align__(16) unsigned char smem[71936];
  const int tid  = threadIdx.x;
  const int wave = tid >> 6;
  const int lane = tid & 63;
  const int l15  = lane & 15;
  const int lhi  = lane >> 4;
  const int wh   = wave >> 2;           // window half 0..1
  const int wc   = wave & 3;            // 96-col quarter

  const int bid = blockIdx.x;           // 0..3071 (= 8 * 384)
  const int l   = (bid & 7) * 384 + (bid >> 3);   // XCD co-location
  const int g2  = l / 3;                // window pair 0..1023
  const int sec = l - g2 * 3;           // 0=q,1=k,2=v
  const int gw  = g2 * 2;               // first window of pair (even)
  const int bIdx = gw >> 10;
  const int win0 = gw & 1023;
  const int wi   = win0 >> 5;
  const int wj0  = win0 & 31;           // even; pair = (wj0, wj0+1), same wi

  auto rowof = [&](int whx, int t)->size_t {
    int r = t / 12, c = t - r * 12;
    int hh = wi * 6 + r + 3;  if (hh >= 192) hh -= 192;
    int ww = (wj0 + whx) * 12 + c + 6; if (ww >= 384) ww -= 384;
    return ((size_t)bIdx * 192 + hh) * 384 + ww;
  };

  float* tabc = reinterpret_cast<float*>(smem + W2TC);
  float* tabs = reinterpret_cast<float*>(smem + W2TS);
  if (tid < 288){
    int pos = tid >> 4, m = tid & 15;
    float pv = (pos < 6) ? (float)pos : (float)(pos - 6);
    float ang = pv * __expf(-(float)m * 0.5756462732485114f); // 10000^(-m/16)
    tabc[tid] = cosf(ang);
    tabs[tid] = sinf(ang);
  }

  // A-chunk precompute (kk-invariant): 1280 chunks = 2 windows x 80 rows x 8
  size_t arow[3]; int asoff[3];
  const bool aval2 = (tid < 256);
  #pragma unroll
  for (int it = 0; it < 3; ++it){
    int c = it * 512 + tid;
    int whx = (c >= 640) ? 1 : 0;
    int r = c - whx * 640;
    int t = r >> 3, p = r & 7;
    int tc = (t < 72) ? t : 71;
    arow[it]  = rowof(whx, tc);
    asoff[it] = ((p ^ (t & 7)) << 3);
  }

  f32x4 acc[5][6];
  #pragma unroll
  for (int mt = 0; mt < 5; ++mt)
    #pragma unroll
    for (int nt = 0; nt < 6; ++nt) acc[mt][nt] = 0.0f;

  for (int kk = 0; kk < 6; ++kk){
    // stage A: 1280 chunks (per-lane gathered rows, both windows)
    #pragma unroll
    for (int it = 0; it < 3; ++it){
      if (it < 2 || aval2)
        glds16(xb + arow[it] * 384 + kk * 64 + asoff[it],
               smem + W2A + (it * 512 + tid) * 16);
    }
    // stage B: 3072 chunks
    #pragma unroll
    for (int it = 0; it < 6; ++it){
      int c = it * 512 + tid;
      int n = c >> 3, p = c & 7;
      glds16(wqb + (size_t)(sec * 384 + n) * 384 + kk * 64 + ((p ^ (n & 7)) << 3),
             smem + W2B + c * 16);
    }
    __syncthreads();
    #pragma unroll
    for (int ks = 0; ks < 2; ++ks){
      const int kEl = ks * 32 + lhi * 8;
      bf16x8 af[5], bfr[6];
      #pragma unroll
      for (int mt = 0; mt < 5; ++mt)
        af[mt] = lds_frag(smem, W2A + wh * 10240, mt * 16 + l15, 128, kEl);
      #pragma unroll
      for (int nt = 0; nt < 6; ++nt)
        bfr[nt] = lds_frag(smem, W2B, wc * 96 + nt * 16 + l15, 128, kEl);
      __builtin_amdgcn_s_setprio(1);
      #pragma unroll
      for (int mt = 0; mt < 5; ++mt)
        #pragma unroll
        for (int nt = 0; nt < 6; ++nt)
          acc[mt][nt] = __builtin_amdgcn_mfma_f32_16x16x32_bf16(af[mt], bfr[nt], acc[mt][nt], 0, 0, 0);
      __builtin_amdgcn_s_setprio(0);
    }
    __syncthreads();
  }

  if (sec < 2){
    // bias + RoPE (+0.125 for q); store window-head-tiled [g][h][72][64]
    const int g = gw + wh;               // this wave's window
    u16* qk = (u16*)out + (sec ? 56623104u : 0u) + (size_t)g * 27648;  // 6*4608
    #pragma unroll
    for (int nt = 0; nt < 6; ++nt){
      const int ch  = wc * 96 + nt * 16 + l15;
      const int h   = ch >> 6;
      const int chh = ch & 63;
      const float bias = bq[sec * 384 + ch];
      const int p2  = chh >> 1;
      const int m   = p2 & 15;
      const bool isR = (p2 < 16);
      const bool ev  = ((chh & 1) == 0);
      #pragma unroll
      for (int mt = 0; mt < 5; ++mt){
        #pragma unroll
        for (int r = 0; r < 4; ++r){
          const int tok = mt * 16 + lhi * 4 + r;
          float v = acc[mt][nt][r] + bias;
          float o = __shfl_xor(v, 1);
          int tr = tok / 12;
          int pos = isR ? tr : (6 + tok - tr * 12);
          float cc = tabc[pos * 16 + m], ssn = tabs[pos * 16 + m];
          float nv = ev ? (v * cc - o * ssn) : (o * ssn + v * cc);
          if (sec == 0) nv *= 0.125f;
          if (tok < 72)
            qk[(size_t)h * 4608 + tok * 64 + chh] = f2bf(nv);
        }
      }
    }
  } else {
    // v: two passes (one window each): bias + transpose into WVT, bulk store
    #pragma unroll
    for (int whp = 0; whp < 2; ++whp){
      if (wh == whp){
        #pragma unroll
        for (int nt = 0; nt < 6; ++nt){
          const int ch = wc * 96 + nt * 16 + l15;
          const float bv = bq[768 + ch];
          #pragma unroll
          for (int mt = 0; mt < 5; ++mt){
            const int tok0 = mt * 16 + lhi * 4;
            uint2 pk;
            pk.x = pkbf(acc[mt][nt][0] + bv, acc[mt][nt][1] + bv);
            pk.y = pkbf(acc[mt][nt][2] + bv, acc[mt][nt][3] + bv);
            *reinterpret_cast<uint2*>(smem + W2VT + ch * 160 + tok0 * 2) = pk;
          }
        }
      }
      __syncthreads();                   // transpose visible to all
      u16* vd = vws + (size_t)(gw + whp) * 30720;   // 6*64*80
      #pragma unroll
      for (int it = 0; it < 8; ++it){
        int c = it * 512 + tid;          // 0..3839 valid
        if (it < 7 || tid < 256){
          int ch = c / 10;
          int p  = c - ch * 10;
          uint4 val;
          if (p == 9){ val.x = 0; val.y = 0; val.z = 0; val.w = 0; }  // toks 72..79
          else val = *reinterpret_cast<const uint4*>(smem + W2VT + c * 16);
          *reinterpret_cast<uint4*>(vd + (size_t)(ch >> 6) * 5120 + (ch & 63) * 80 + p * 8) = val;
        }
      }
      __syncthreads();                   // reads done before next pass rewrites
    }
  }
}

// ============ K3 v10: per-window attention, ALL inputs linear glds16 ============
// q,k from out (window-head-tiled), v from vws [g][h][64][80] (pre-transposed,
// pads zeroed). attnout -> axb [row][384] u16. (unchanged from r11)
#define QH4 0
#define KH4 10240
#define VT4 20480      // 64*160 + 256 guard -> 30976
#define SMEM4 30976
__launch_bounds__(320, 5)
__global__ void win_attn6(const u16* __restrict__ qkg,
                          const u16* __restrict__ vws,
                          float* __restrict__ out,
                          u16* __restrict__ axb)
{
  __shared__ __align__(16) unsigned char smem[SMEM4];
  const int tid  = threadIdx.x;
  const int wave = tid >> 6;
  const int lane = tid & 63;
  const int l15  = lane & 15;
  const int lhi  = lane >> 4;

  const int bid  = blockIdx.x;
  const int wgid = (bid & 7) * 256 + (bid >> 3);   // XCD swizzle (2048 = 8*256)
  const int bIdx = wgid >> 10;
  const int win  = wgid & 1023;
  const int wi   = win >> 5;
  const int wj   = win & 31;
  const bool maskWin = (wi == 31);
  const int g    = wgid;

  auto rowof = [&](int t)->size_t {
    int r = t / 12, c = t - r * 12;
    int hh = wi * 6 + r + 3;  if (hh >= 192) hh -= 192;
    int ww = wj * 12 + c + 6; if (ww >= 384) ww -= 384;
    return ((size_t)bIdx * 192 + hh) * 384 + ww;
  };
  const int qtok = wave * 16 + l15;     // 0..79
  const bool tv = (qtok < 72);
  const size_t qrow = rowof(tv ? qtok : 71);

  const u16* qsl0 = qkg + (size_t)g * 27648;
  const u16* ksl0 = qkg + 56623104u + (size_t)g * 27648;
  const u16* vsl0 = vws + (size_t)g * 30720;

  // zero the VT guard (row-overhang reads for kEl>=80 land here)
  if (tid < 64) *reinterpret_cast<u32*>(smem + VT4 + 10240 + tid * 4) = 0u;

  float sv[5][4];
  #pragma unroll
  for (int a2 = 0; a2 < 5; ++a2)
    #pragma unroll
    for (int b2 = 0; b2 < 4; ++b2) sv[a2][b2] = 0.0f;

  for (int h = 0; h < 6; ++h){
    // ---- stage q,k (pre-swizzled src) and v (linear) : 1920 glds16 ----
    const u16* qsl = qsl0 + h * 4608;
    const u16* ksl = ksl0 + h * 4608;
    const u16* vsl = vsl0 + h * 5120;
    #pragma unroll
    for (int it = 0; it < 2; ++it){
      int c = it * 320 + tid;           // 0..639
      int t = c >> 3, p = c & 7;
      int tc = (t < 72) ? t : 71;
      int s = (p ^ (t & 7)) << 3;
      glds16(qsl + tc * 64 + s, smem + QH4 + c * 16);
      glds16(ksl + tc * 64 + s, smem + KH4 + c * 16);
      glds16(vsl + c * 8,       smem + VT4 + c * 16);
    }
    __syncthreads();                    // stage visible

    // ---- QK^T: C[i=k][j=q] ----
    f32x4 pf[5];
    #pragma unroll
    for (int nt = 0; nt < 5; ++nt) pf[nt] = 0.0f;
    __builtin_amdgcn_s_setprio(1);
    #pragma unroll
    for (int ks = 0; ks < 2; ++ks){
      const int kEl = ks * 32 + lhi * 8;
      bf16x8 qf = lds_frag(smem, QH4, qtok, 128, kEl);
      #pragma unroll
      for (int nt = 0; nt < 5; ++nt){
        bf16x8 kf = lds_frag(smem, KH4, nt * 16 + l15, 128, kEl);
        pf[nt] = __builtin_amdgcn_mfma_f32_16x16x32_bf16(kf, qf, pf[nt], 0, 0, 0);
      }
    }
    __builtin_amdgcn_s_setprio(0);

    // ---- mask + softmax over k ----
    float mx = -1e30f;
    #pragma unroll
    for (int nt = 0; nt < 5; ++nt)
      #pragma unroll
      for (int r = 0; r < 4; ++r){
        const int kk2 = nt * 16 + lhi * 4 + r;
        bool valid = (kk2 < 72) && (!maskWin || ((kk2 < 36) == (qtok < 36)));
        float val = valid ? pf[nt][r] : -1e30f;
        pf[nt][r] = val;
        mx = fmaxf(mx, val);
      }
    mx = fmaxf(mx, __shfl_xor(mx, 16));
    mx = fmaxf(mx, __shfl_xor(mx, 32));
    float sm = 0.0f;
    #pragma unroll
    for (int nt = 0; nt < 5; ++nt)
      #pragma unroll
      for (int r = 0; r < 4; ++r){
        float e = __expf(pf[nt][r] - mx);
        pf[nt][r] = e; sm += e;
      }
    sm += __shfl_xor(sm, 16);
    sm += __shfl_xor(sm, 32);
    const float inv = 1.0f / sm;
    u32 pp[5][2];                       // packed bf16 pairs: P[k..k+1][q=l15]
    #pragma unroll
    for (int nt = 0; nt < 5; ++nt){
      float p0 = pf[nt][0] * inv, p1 = pf[nt][1] * inv;
      float p2 = pf[nt][2] * inv, p3 = pf[nt][3] * inv;
      sv[nt][0] += p0; sv[nt][1] += p1; sv[nt][2] += p2; sv[nt][3] += p3;
      pp[nt][0] = pkbf(p0, p1);
      pp[nt][1] = pkbf(p2, p3);
    }

    // ---- PV: C[i=ch][j=q]; P B-frags via shfl; V^T direct from VT ----
    f32x4 oacc[4];
    #pragma unroll
    for (int nt = 0; nt < 4; ++nt) oacc[nt] = 0.0f;
    #pragma unroll
    for (int ks = 0; ks < 3; ++ks){
      FragU pb;
      u32 w[4];
      #pragma unroll
      for (int w_ = 0; w_ < 4; ++w_){
        int srcLane = l15 + 16 * ((lane >> 4 & 1) * 2 + (w_ >> 1));
        u32 c0 = __shfl(pp[ks * 2][w_ & 1], srcLane);
        u32 c1 = (ks * 2 + 1 < 5) ? __shfl(pp[ks * 2 + 1][w_ & 1], srcLane) : 0u;
        w[w_] = (lhi & 2) ? c1 : c0;
      }
      pb.u4.x = w[0]; pb.u4.y = w[1]; pb.u4.z = w[2]; pb.u4.w = w[3];
      const int kEl = ks * 32 + lhi * 8;
      __builtin_amdgcn_s_setprio(1);
      #pragma unroll
      for (int nt = 0; nt < 4; ++nt){
        FragU vf;
        vf.u4 = *reinterpret_cast<const uint4*>(smem + VT4 + (nt * 16 + l15) * 160 + kEl * 2);
        oacc[nt] = __builtin_amdgcn_mfma_f32_16x16x32_bf16(vf.bf, pb.bf, oacc[nt], 0, 0, 0);
      }
      __builtin_amdgcn_s_setprio(0);
    }
    if (tv){
      u16* ao = axb + qrow * 384 + h * 64;
      #pragma unroll
      for (int nt = 0; nt < 4; ++nt){
        uint2 pk;
        pk.x = pkbf(oacc[nt][0], oacc[nt][1]);
        pk.y = pkbf(oacc[nt][2], oacc[nt][3]);
        *reinterpret_cast<uint2*>(ao + nt * 16 + lhi * 4) = pk;
      }
    }
    __syncthreads();                    // all LDS reads done before next stage
  } // heads

  // ---- save_attn = mean over heads: so[q*72 + k] ----
  if (tv){
    float* so = out + 56623104ull + (size_t)wgid * 5184 + (size_t)qtok * 72;
    const float c6 = 1.0f / 6.0f;
    #pragma unroll
    for (int nt = 0; nt < 4; ++nt){
      float4 v4; v4.x = sv[nt][0]*c6; v4.y = sv[nt][1]*c6; v4.z = sv[nt][2]*c6; v4.w = sv[nt][3]*c6;
      *reinterpret_cast<float4*>(so + nt * 16 + lhi * 4) = v4;
    }
    if (lhi < 2){
      float4 v4; v4.x = sv[4][0]*c6; v4.y = sv[4][1]*c6; v4.z = sv[4][2]*c6; v4.w = sv[4][3]*c6;
      *reinterpret_cast<float4*>(so + 64 + lhi * 4) = v4;
    }
  }
}

// ======================================================================
// K4 v12: out-projection GEMM (r7/r9 inner structure) with flat grid +
// XCD co-location: the 2 ny-variants of one 128-row block share the A
// panel in their XCD's L2. grid 2304 (= 8*288).
// ======================================================================
#define B6STR 12288
__launch_bounds__(512, 4)
__global__ void proj_gemm2(const u16* __restrict__ axb,
                           const u16* __restrict__ wpb, const float* __restrict__ bp,
                           float* __restrict__ out)
{
  __shared__ __align__(16) unsigned char smem[24576];
  const int tid  = threadIdx.x;
  const int wave = tid >> 6;
  const int lane = tid & 63;
  const int l15  = lane & 15;
  const int lhi  = lane >> 4;
  const int wr   = wave >> 2;
  const int wc   = wave & 3;

  const int bid = blockIdx.x;           // 0..2303
  const int l   = (bid & 7) * 288 + (bid >> 3);
  const size_t row0 = (size_t)(l >> 1) * 128;
  const int ny  = l & 1;

  const u16* bsec = wpb + (size_t)(ny * 192) * 384;
  auto stageB = [&](int t, int bufOff){
    {
      int c = tid, row = c >> 2, ccd = c & 3;
      int ccs = ccd ^ ((row >> 1) & 3);
      glds16(bsec + (size_t)row * 384 + t * 32 + ccs * 8, smem + bufOff + c * 16);
    }
    if (tid < 256){
      int c = 512 + tid, row = c >> 2, ccd = c & 3;
      int ccs = ccd ^ ((row >> 1) & 3);
      glds16(bsec + (size_t)row * 384 + t * 32 + ccs * 8, smem + bufOff + c * 16);
    }
  };

  const u16* abase = axb + (row0 + wr * 64 + l15) * 384 + lhi * 8;

  f32x4 acc[4][3];
  #pragma unroll
  for (int mt = 0; mt < 4; ++mt)
    #pragma unroll
    for (int nt = 0; nt < 3; ++nt) acc[mt][nt] = 0.0f;

  FragU a_cur[4], a_nxt[4];
  #pragma unroll
  for (int mt = 0; mt < 4; ++mt)
    a_cur[mt].u4 = *reinterpret_cast<const uint4*>(abase + mt * 6144);
  stageB(0, 0);
  __syncthreads();

  int buf = 0;
  for (int t = 0; t < 12; ++t){
    if (t < 11){
      stageB(t + 1, buf ^ B6STR);
      #pragma unroll
      for (int mt = 0; mt < 4; ++mt)
        a_nxt[mt].u4 = *reinterpret_cast<const uint4*>(abase + mt * 6144 + (t + 1) * 32);
    }
    FragU bfr[3];
    #pragma unroll
    for (int nt = 0; nt < 3; ++nt){
      int rown = wc * 48 + nt * 16 + l15;
      int byte = buf + rown * 64 + ((lhi ^ ((rown >> 1) & 3)) << 4);
      bfr[nt].u4 = *reinterpret_cast<const uint4*>(smem + byte);
    }
    #pragma unroll
    for (int mt = 0; mt < 4; ++mt)
      #pragma unroll
      for (int nt = 0; nt < 3; ++nt)
        acc[mt][nt] = __builtin_amdgcn_mfma_f32_16x16x32_bf16(a_cur[mt].bf, bfr[nt].bf, acc[mt][nt], 0, 0, 0);
    __syncthreads();
    #pragma unroll
    for (int mt = 0; mt < 4; ++mt) a_cur[mt] = a_nxt[mt];
    buf ^= B6STR;
  }

  float bpv[3];
  #pragma unroll
  for (int nt = 0; nt < 3; ++nt) bpv[nt] = bp[ny * 192 + wc * 48 + nt * 16 + l15];
  #pragma unroll
  for (int mt = 0; mt < 4; ++mt)
    #pragma unroll
    for (int nt = 0; nt < 3; ++nt){
      const int ch = ny * 192 + wc * 48 + nt * 16 + l15;
      #pragma unroll
      for (int r = 0; r < 4; ++r){
        size_t grow = row0 + wr * 64 + mt * 16 + lhi * 4 + r;
        out[grow * 384 + ch] = acc[mt][nt][r] + bpv[nt];
      }
    }
}

extern "C" void kernel_launch(void* const* d_in, const int* in_sizes, int n_in,
                              void* d_out, int out_size, void* d_ws, size_t ws_size,
                              hipStream_t stream)
{
  const float* x  = (const float*)d_in[0];
  const float* wq = (const float*)d_in[1];
  const float* bq = (const float*)d_in[2];
  const float* wp = (const float*)d_in[3];
  const float* bp = (const float*)d_in[4];
  float* out = (float*)d_out;

  u16* wqb = (u16*)d_ws;                              // 442368 bf16
  u16* wpb = (u16*)((char*)d_ws + 442368 * 2);        // 147456 bf16
  u16* vws = (u16*)((char*)d_ws + 1179648);           // 2048*6*64*80 bf16 (125.8 MB)
  u16* xb  = (u16*)((char*)d_ws + 127008768);         // 147456*384 bf16 (113.2 MB)
  // ws_size >= 240254976 confirmed by rounds 5/7/9 (big2 path ran).

  prep_weights<<<1728, 256, 0, stream>>>(wq, wp, wqb, wpb);
  prep_x<<<27648, 256, 0, stream>>>(x, xb);
  qkv_win2<<<3072, 512, 0, stream>>>(xb, wqb, bq, out, vws);
  win_attn6<<<2048, 320, 0, stream>>>((const u16*)out, vws, out, xb);
  proj_gemm2<<<2304, 512, 0, stream>>>(xb, wpb, bp, out);
}

// Round 13
// 644.088 us; speedup vs baseline: 1.0052x; 1.0052x over previous
//
#include <hip/hip_runtime.h>

typedef __attribute__((ext_vector_type(8))) __bf16 bf16x8;
typedef __attribute__((ext_vector_type(4))) float f32x4;
typedef unsigned short u16;
typedef unsigned int u32;

__device__ __forceinline__ u16 f2bf(float x){
  u32 u = __float_as_uint(x);
  return (u16)((u + 0x7fffu + ((u >> 16) & 1u)) >> 16);
}
__device__ __forceinline__ u32 pkbf(float lo, float hi){
  u32 r; asm("v_cvt_pk_bf16_f32 %0, %1, %2" : "=v"(r) : "v"(lo), "v"(hi)); return r;
}

union FragU { uint4 u4; bf16x8 bf; };

__device__ __forceinline__ bf16x8 lds_frag(const unsigned char* smem, int off, int row, int strideB, int kElem){
  int byte = (row * strideB + kElem * 2) ^ ((row & 7) << 4);
  FragU f; f.u4 = *reinterpret_cast<const uint4*>(smem + off + byte);
  return f.bf;
}

typedef __attribute__((address_space(3))) unsigned char lds_u8;
typedef __attribute__((address_space(1))) const unsigned char g_u8;
__device__ __forceinline__ void glds16(const void* g, void* l){
  __builtin_amdgcn_global_load_lds((g_u8*)g, (lds_u8*)l, 16, 0, 0);
}

__global__ void prep_weights(const float* __restrict__ wq, const float* __restrict__ wp,
                             u16* __restrict__ wqb, u16* __restrict__ wpb){
  int i = blockIdx.x * 256 + threadIdx.x;
  wqb[i] = f2bf(wq[i]);              // grid sized exactly for 442368
  if (i < 147456) wpb[i] = f2bf(wp[i]);
}

// x f32 -> bf16, linear [147456][384]
__global__ void prep_x(const float* __restrict__ x, u16* __restrict__ xb){
  size_t i = ((size_t)blockIdx.x * 256 + threadIdx.x) * 8;
  float4 f0 = *reinterpret_cast<const float4*>(x + i);
  float4 f1 = *reinterpret_cast<const float4*>(x + i + 4);
  uint4 q;
  q.x = pkbf(f0.x, f0.y); q.y = pkbf(f0.z, f0.w);
  q.z = pkbf(f1.x, f1.y); q.w = pkbf(f1.z, f1.w);
  *reinterpret_cast<uint4*>(xb + i) = q;
}

// ======================================================================
// K2: WINDOW-MAJOR qkv GEMM (r11 proven, 296us). One (window, sec) per
// block, 256 thr. q/k window-head-tiled into out; v transposed in LDS to
// vws[g][h][64ch][80tok] (toks 72..79 zeroed).
// ======================================================================
#define WA_OFF 0        // A [80][64] bf16 swz : 10240
#define WB_OFF 10240    // B [384][64] bf16 swz : 49152 -> 59392
#define WVT    0        // v-transpose [384ch][80tok] (aliases A+B post-loop)
#define WTC    61440    // 288 f32
#define WTS    62592    // -> 63744
__launch_bounds__(256, 2)
__global__ void qkv_win(const u16* __restrict__ xb, const u16* __restrict__ wqb,
                        const float* __restrict__ bq, float* __restrict__ out,
                        u16* __restrict__ vws)
{
  __shared__ __align__(16) unsigned char smem[63744];
  const int tid  = threadIdx.x;
  const int wc   = tid >> 6;            // wave 0..3 : 96-col quarter
  const int lane = tid & 63;
  const int l15  = lane & 15;
  const int lhi  = lane >> 4;

  const int bid = blockIdx.x;           // 0..6143 (= 8 * 768)
  const int l   = (bid & 7) * 768 + (bid >> 3);
  const int g   = l / 3;                // global window 0..2047
  const int sec = l - g * 3;            // 0=q,1=k,2=v
  const int bIdx = g >> 10;
  const int win  = g & 1023;
  const int wi   = win >> 5;
  const int wj   = win & 31;

  auto rowof = [&](int t)->size_t {
    int r = t / 12, c = t - r * 12;
    int hh = wi * 6 + r + 3;  if (hh >= 192) hh -= 192;
    int ww = wj * 12 + c + 6; if (ww >= 384) ww -= 384;
    return ((size_t)bIdx * 192 + hh) * 384 + ww;
  };

  float* tabc = reinterpret_cast<float*>(smem + WTC);
  float* tabs = reinterpret_cast<float*>(smem + WTS);
  for (int i = tid; i < 288; i += 256){
    int pos = i >> 4, m = i & 15;
    float pv = (pos < 6) ? (float)pos : (float)(pos - 6);
    float ang = pv * __expf(-(float)m * 0.5756462732485114f); // 10000^(-m/16)
    tabc[i] = cosf(ang);
    tabs[i] = sinf(ang);
  }

  // precompute A-chunk source rows (kk-invariant)
  size_t arow[3]; int asoff[3]; bool aval[3];
  #pragma unroll
  for (int it = 0; it < 3; ++it){
    int c = it * 256 + tid;
    aval[it] = (it < 2) || (tid < 128);
    int t = c >> 3, p = c & 7;
    int tc = (t < 72) ? t : 71;
    arow[it]  = rowof(tc);
    asoff[it] = ((p ^ (t & 7)) << 3);
  }

  f32x4 acc[5][6];
  #pragma unroll
  for (int mt = 0; mt < 5; ++mt)
    #pragma unroll
    for (int nt = 0; nt < 6; ++nt) acc[mt][nt] = 0.0f;

  for (int kk = 0; kk < 6; ++kk){
    #pragma unroll
    for (int it = 0; it < 3; ++it){
      if (aval[it])
        glds16(xb + arow[it] * 384 + kk * 64 + asoff[it],
               smem + WA_OFF + (it * 256 + tid) * 16);
    }
    #pragma unroll
    for (int it = 0; it < 12; ++it){
      int c = it * 256 + tid;
      int n = c >> 3, p = c & 7;
      glds16(wqb + (size_t)(sec * 384 + n) * 384 + kk * 64 + ((p ^ (n & 7)) << 3),
             smem + WB_OFF + c * 16);
    }
    __syncthreads();
    #pragma unroll
    for (int ks = 0; ks < 2; ++ks){
      const int kEl = ks * 32 + lhi * 8;
      bf16x8 af[5], bfr[6];
      #pragma unroll
      for (int mt = 0; mt < 5; ++mt)
        af[mt] = lds_frag(smem, WA_OFF, mt * 16 + l15, 128, kEl);
      #pragma unroll
      for (int nt = 0; nt < 6; ++nt)
        bfr[nt] = lds_frag(smem, WB_OFF, wc * 96 + nt * 16 + l15, 128, kEl);
      __builtin_amdgcn_s_setprio(1);
      #pragma unroll
      for (int mt = 0; mt < 5; ++mt)
        #pragma unroll
        for (int nt = 0; nt < 6; ++nt)
          acc[mt][nt] = __builtin_amdgcn_mfma_f32_16x16x32_bf16(af[mt], bfr[nt], acc[mt][nt], 0, 0, 0);
      __builtin_amdgcn_s_setprio(0);
    }
    __syncthreads();
  }

  if (sec < 2){
    u16* qk = (u16*)out + (sec ? 56623104u : 0u) + (size_t)g * 27648;  // 6*4608
    #pragma unroll
    for (int nt = 0; nt < 6; ++nt){
      const int ch  = wc * 96 + nt * 16 + l15;
      const int h   = ch >> 6;
      const int chh = ch & 63;
      const float bias = bq[sec * 384 + ch];
      const int p2  = chh >> 1;
      const int m   = p2 & 15;
      const bool isR = (p2 < 16);
      const bool ev  = ((chh & 1) == 0);
      #pragma unroll
      for (int mt = 0; mt < 5; ++mt){
        #pragma unroll
        for (int r = 0; r < 4; ++r){
          const int tok = mt * 16 + lhi * 4 + r;
          float v = acc[mt][nt][r] + bias;
          float o = __shfl_xor(v, 1);
          int tr = tok / 12;
          int pos = isR ? tr : (6 + tok - tr * 12);
          float cc = tabc[pos * 16 + m], ssn = tabs[pos * 16 + m];
          float nv = ev ? (v * cc - o * ssn) : (o * ssn + v * cc);
          if (sec == 0) nv *= 0.125f;
          if (tok < 72)
            qk[(size_t)h * 4608 + tok * 64 + chh] = f2bf(nv);
        }
      }
    }
  } else {
    #pragma unroll
    for (int nt = 0; nt < 6; ++nt){
      const int ch = wc * 96 + nt * 16 + l15;
      const float bv = bq[768 + ch];
      #pragma unroll
      for (int mt = 0; mt < 5; ++mt){
        const int tok0 = mt * 16 + lhi * 4;
        uint2 pk;
        pk.x = pkbf(acc[mt][nt][0] + bv, acc[mt][nt][1] + bv);
        pk.y = pkbf(acc[mt][nt][2] + bv, acc[mt][nt][3] + bv);
        *reinterpret_cast<uint2*>(smem + WVT + ch * 160 + tok0 * 2) = pk;
      }
    }
    __syncthreads();
    u16* vd = vws + (size_t)g * 30720;   // 6*64*80
    #pragma unroll
    for (int it = 0; it < 15; ++it){
      int c  = it * 256 + tid;           // 0..3839
      int ch = c / 10;
      int p  = c - ch * 10;
      uint4 val;
      if (p == 9){ val.x = 0; val.y = 0; val.z = 0; val.w = 0; }  // tok 72..79 = 0
      else val = *reinterpret_cast<const uint4*>(smem + WVT + c * 16);
      *reinterpret_cast<uint4*>(vd + (size_t)(ch >> 6) * 5120 + (ch & 63) * 80 + p * 8) = val;
    }
  }
}

// ======================================================================
// K3 v13: per-window attention with HEAD-DOUBLE-BUFFERED staging.
// stage(h+1) issued right after the barrier that publishes buf[h]; the
// prefetch stays in flight across the whole compute(h) phase and is
// drained by the NEXT iteration's barrier (one barrier per head).
// LDS 2 x {QH,KH,VT+guard} = 61952 B -> 2 blocks/CU.
// ======================================================================
#define AB_Q 0
#define AB_K 10240
#define AB_V 20480     // VT 10240 + 256 guard
#define AB_SZ 30976    // per-buffer size; SMEM = 2*AB_SZ
__launch_bounds__(320, 3)
__global__ void win_attn7(const u16* __restrict__ qkg,
                          const u16* __restrict__ vws,
                          float* __restrict__ out,
                          u16* __restrict__ axb)
{
  __shared__ __align__(16) unsigned char smem[2 * AB_SZ];
  const int tid  = threadIdx.x;
  const int wave = tid >> 6;
  const int lane = tid & 63;
  const int l15  = lane & 15;
  const int lhi  = lane >> 4;

  const int bid  = blockIdx.x;
  const int wgid = (bid & 7) * 256 + (bid >> 3);   // XCD swizzle = qkv's map
  const int bIdx = wgid >> 10;
  const int win  = wgid & 1023;
  const int wi   = win >> 5;
  const int wj   = win & 31;
  const bool maskWin = (wi == 31);
  const int g    = wgid;

  auto rowof = [&](int t)->size_t {
    int r = t / 12, c = t - r * 12;
    int hh = wi * 6 + r + 3;  if (hh >= 192) hh -= 192;
    int ww = wj * 12 + c + 6; if (ww >= 384) ww -= 384;
    return ((size_t)bIdx * 192 + hh) * 384 + ww;
  };
  const int qtok = wave * 16 + l15;     // 0..79
  const bool tv = (qtok < 72);
  const size_t qrow = rowof(tv ? qtok : 71);

  const u16* qsl0 = qkg + (size_t)g * 27648;
  const u16* ksl0 = qkg + 56623104u + (size_t)g * 27648;
  const u16* vsl0 = vws + (size_t)g * 30720;

  // zero both VT guards (overhang reads for kEl>=80 land here; must be 0)
  if (tid < 64){
    *reinterpret_cast<u32*>(smem + AB_V + 10240 + tid * 4) = 0u;
    *reinterpret_cast<u32*>(smem + AB_SZ + AB_V + 10240 + tid * 4) = 0u;
  }

  auto stage_head = [&](int h, unsigned char* base){
    const u16* qsl = qsl0 + h * 4608;
    const u16* ksl = ksl0 + h * 4608;
    const u16* vsl = vsl0 + h * 5120;
    #pragma unroll
    for (int it = 0; it < 2; ++it){
      int c = it * 320 + tid;           // 0..639
      int t = c >> 3, p = c & 7;
      int tc = (t < 72) ? t : 71;
      int s = (p ^ (t & 7)) << 3;
      glds16(qsl + tc * 64 + s, base + AB_Q + c * 16);
      glds16(ksl + tc * 64 + s, base + AB_K + c * 16);
      glds16(vsl + c * 8,       base + AB_V + c * 16);
    }
  };

  float sv[5][4];
  #pragma unroll
  for (int a2 = 0; a2 < 5; ++a2)
    #pragma unroll
    for (int b2 = 0; b2 < 4; ++b2) sv[a2][b2] = 0.0f;

  stage_head(0, smem);                  // prologue stage

  for (int h = 0; h < 6; ++h){
    unsigned char* cur = smem + (h & 1) * AB_SZ;
    __syncthreads();                    // buf[cur] staged (drains prefetch)
    if (h < 5) stage_head(h + 1, smem + ((h + 1) & 1) * AB_SZ);  // in flight over compute

    // ---- QK^T: C[i=k][j=q] ----
    f32x4 pf[5];
    #pragma unroll
    for (int nt = 0; nt < 5; ++nt) pf[nt] = 0.0f;
    __builtin_amdgcn_s_setprio(1);
    #pragma unroll
    for (int ks = 0; ks < 2; ++ks){
      const int kEl = ks * 32 + lhi * 8;
      bf16x8 qf = lds_frag(cur, AB_Q, qtok, 128, kEl);
      #pragma unroll
      for (int nt = 0; nt < 5; ++nt){
        bf16x8 kf = lds_frag(cur, AB_K, nt * 16 + l15, 128, kEl);
        pf[nt] = __builtin_amdgcn_mfma_f32_16x16x32_bf16(kf, qf, pf[nt], 0, 0, 0);
      }
    }
    __builtin_amdgcn_s_setprio(0);

    // ---- mask + softmax over k ----
    float mx = -1e30f;
    #pragma unroll
    for (int nt = 0; nt < 5; ++nt)
      #pragma unroll
      for (int r = 0; r < 4; ++r){
        const int kk2 = nt * 16 + lhi * 4 + r;
        bool valid = (kk2 < 72) && (!maskWin || ((kk2 < 36) == (qtok < 36)));
        float val = valid ? pf[nt][r] : -1e30f;
        pf[nt][r] = val;
        mx = fmaxf(mx, val);
      }
    mx = fmaxf(mx, __shfl_xor(mx, 16));
    mx = fmaxf(mx, __shfl_xor(mx, 32));
    float sm = 0.0f;
    #pragma unroll
    for (int nt = 0; nt < 5; ++nt)
      #pragma unroll
      for (int r = 0; r < 4; ++r){
        float e = __expf(pf[nt][r] - mx);
        pf[nt][r] = e; sm += e;
      }
    sm += __shfl_xor(sm, 16);
    sm += __shfl_xor(sm, 32);
    const float inv = 1.0f / sm;
    u32 pp[5][2];                       // packed bf16 pairs: P[k..k+1][q=l15]
    #pragma unroll
    for (int nt = 0; nt < 5; ++nt){
      float p0 = pf[nt][0] * inv, p1 = pf[nt][1] * inv;
      float p2 = pf[nt][2] * inv, p3 = pf[nt][3] * inv;
      sv[nt][0] += p0; sv[nt][1] += p1; sv[nt][2] += p2; sv[nt][3] += p3;
      pp[nt][0] = pkbf(p0, p1);
      pp[nt][1] = pkbf(p2, p3);
    }

    // ---- PV: C[i=ch][j=q]; P B-frags via shfl; V^T direct from VT ----
    f32x4 oacc[4];
    #pragma unroll
    for (int nt = 0; nt < 4; ++nt) oacc[nt] = 0.0f;
    #pragma unroll
    for (int ks = 0; ks < 3; ++ks){
      FragU pb;
      u32 w[4];
      #pragma unroll
      for (int w_ = 0; w_ < 4; ++w_){
        int srcLane = l15 + 16 * ((lane >> 4 & 1) * 2 + (w_ >> 1));
        u32 c0 = __shfl(pp[ks * 2][w_ & 1], srcLane);
        u32 c1 = (ks * 2 + 1 < 5) ? __shfl(pp[ks * 2 + 1][w_ & 1], srcLane) : 0u;
        w[w_] = (lhi & 2) ? c1 : c0;
      }
      pb.u4.x = w[0]; pb.u4.y = w[1]; pb.u4.z = w[2]; pb.u4.w = w[3];
      const int kEl = ks * 32 + lhi * 8;
      __builtin_amdgcn_s_setprio(1);
      #pragma unroll
      for (int nt = 0; nt < 4; ++nt){
        FragU vf;
        vf.u4 = *reinterpret_cast<const uint4*>(cur + AB_V + (nt * 16 + l15) * 160 + kEl * 2);
        oacc[nt] = __builtin_amdgcn_mfma_f32_16x16x32_bf16(vf.bf, pb.bf, oacc[nt], 0, 0, 0);
      }
      __builtin_amdgcn_s_setprio(0);
    }
    if (tv){
      u16* ao = axb + qrow * 384 + h * 64;
      #pragma unroll
      for (int nt = 0; nt < 4; ++nt){
        uint2 pk;
        pk.x = pkbf(oacc[nt][0], oacc[nt][1]);
        pk.y = pkbf(oacc[nt][2], oacc[nt][3]);
        *reinterpret_cast<uint2*>(ao + nt * 16 + lhi * 4) = pk;
      }
    }
    // no trailing barrier: next iteration's loop-top barrier protects reuse
  } // heads

  // ---- save_attn = mean over heads: so[q*72 + k] ----
  if (tv){
    float* so = out + 56623104ull + (size_t)wgid * 5184 + (size_t)qtok * 72;
    const float c6 = 1.0f / 6.0f;
    #pragma unroll
    for (int nt = 0; nt < 4; ++nt){
      float4 v4; v4.x = sv[nt][0]*c6; v4.y = sv[nt][1]*c6; v4.z = sv[nt][2]*c6; v4.w = sv[nt][3]*c6;
      *reinterpret_cast<float4*>(so + nt * 16 + lhi * 4) = v4;
    }
    if (lhi < 2){
      float4 v4; v4.x = sv[4][0]*c6; v4.y = sv[4][1]*c6; v4.z = sv[4][2]*c6; v4.w = sv[4][3]*c6;
      *reinterpret_cast<float4*>(so + 64 + lhi * 4) = v4;
    }
  }
}

// ======================================================================
// K4: out-projection GEMM (r12): tile M=128 x N=192, BK=32, 2-phase dbuf
// B, A frags from axb; flat grid 2304 with XCD co-location of ny-pairs.
// ======================================================================
#define B6STR 12288
__launch_bounds__(512, 4)
__global__ void proj_gemm2(const u16* __restrict__ axb,
                           const u16* __restrict__ wpb, const float* __restrict__ bp,
                           float* __restrict__ out)
{
  __shared__ __align__(16) unsigned char smem[24576];
  const int tid  = threadIdx.x;
  const int wave = tid >> 6;
  const int lane = tid & 63;
  const int l15  = lane & 15;
  const int lhi  = lane >> 4;
  const int wr   = wave >> 2;
  const int wc   = wave & 3;

  const int bid = blockIdx.x;           // 0..2303
  const int l   = (bid & 7) * 288 + (bid >> 3);
  const size_t row0 = (size_t)(l >> 1) * 128;
  const int ny  = l & 1;

  const u16* bsec = wpb + (size_t)(ny * 192) * 384;
  auto stageB = [&](int t, int bufOff){
    {
      int c = tid, row = c >> 2, ccd = c & 3;
      int ccs = ccd ^ ((row >> 1) & 3);
      glds16(bsec + (size_t)row * 384 + t * 32 + ccs * 8, smem + bufOff + c * 16);
    }
    if (tid < 256){
      int c = 512 + tid, row = c >> 2, ccd = c & 3;
      int ccs = ccd ^ ((row >> 1) & 3);
      glds16(bsec + (size_t)row * 384 + t * 32 + ccs * 8, smem + bufOff + c * 16);
    }
  };

  const u16* abase = axb + (row0 + wr * 64 + l15) * 384 + lhi * 8;

  f32x4 acc[4][3];
  #pragma unroll
  for (int mt = 0; mt < 4; ++mt)
    #pragma unroll
    for (int nt = 0; nt < 3; ++nt) acc[mt][nt] = 0.0f;

  FragU a_cur[4], a_nxt[4];
  #pragma unroll
  for (int mt = 0; mt < 4; ++mt)
    a_cur[mt].u4 = *reinterpret_cast<const uint4*>(abase + mt * 6144);
  stageB(0, 0);
  __syncthreads();

  int buf = 0;
  for (int t = 0; t < 12; ++t){
    if (t < 11){
      stageB(t + 1, buf ^ B6STR);
      #pragma unroll
      for (int mt = 0; mt < 4; ++mt)
        a_nxt[mt].u4 = *reinterpret_cast<const uint4*>(abase + mt * 6144 + (t + 1) * 32);
    }
    FragU bfr[3];
    #pragma unroll
    for (int nt = 0; nt < 3; ++nt){
      int rown = wc * 48 + nt * 16 + l15;
      int byte = buf + rown * 64 + ((lhi ^ ((rown >> 1) & 3)) << 4);
      bfr[nt].u4 = *reinterpret_cast<const uint4*>(smem + byte);
    }
    #pragma unroll
    for (int mt = 0; mt < 4; ++mt)
      #pragma unroll
      for (int nt = 0; nt < 3; ++nt)
        acc[mt][nt] = __builtin_amdgcn_mfma_f32_16x16x32_bf16(a_cur[mt].bf, bfr[nt].bf, acc[mt][nt], 0, 0, 0);
    __syncthreads();
    #pragma unroll
    for (int mt = 0; mt < 4; ++mt) a_cur[mt] = a_nxt[mt];
    buf ^= B6STR;
  }

  float bpv[3];
  #pragma unroll
  for (int nt = 0; nt < 3; ++nt) bpv[nt] = bp[ny * 192 + wc * 48 + nt * 16 + l15];
  #pragma unroll
  for (int mt = 0; mt < 4; ++mt)
    #pragma unroll
    for (int nt = 0; nt < 3; ++nt){
      const int ch = ny * 192 + wc * 48 + nt * 16 + l15;
      #pragma unroll
      for (int r = 0; r < 4; ++r){
        size_t grow = row0 + wr * 64 + mt * 16 + lhi * 4 + r;
        out[grow * 384 + ch] = acc[mt][nt][r] + bpv[nt];
      }
    }
}

extern "C" void kernel_launch(void* const* d_in, const int* in_sizes, int n_in,
                              void* d_out, int out_size, void* d_ws, size_t ws_size,
                              hipStream_t stream)
{
  const float* x  = (const float*)d_in[0];
  const float* wq = (const float*)d_in[1];
  const float* bq = (const float*)d_in[2];
  const float* wp = (const float*)d_in[3];
  const float* bp = (const float*)d_in[4];
  float* out = (float*)d_out;

  u16* wqb = (u16*)d_ws;                              // 442368 bf16
  u16* wpb = (u16*)((char*)d_ws + 442368 * 2);        // 147456 bf16
  u16* vws = (u16*)((char*)d_ws + 1179648);           // 2048*6*64*80 bf16 (125.8 MB)
  u16* xb  = (u16*)((char*)d_ws + 127008768);         // 147456*384 bf16 (113.2 MB)
  // ws_size >= 240254976 confirmed by rounds 5/7/9 (big2 path ran).

  prep_weights<<<1728, 256, 0, stream>>>(wq, wp, wqb, wpb);
  prep_x<<<27648, 256, 0, stream>>>(x, xb);
  qkv_win<<<6144, 256, 0, stream>>>(xb, wqb, bq, out, vws);
  win_attn7<<<2048, 320, 0, stream>>>((const u16*)out, vws, out, xb);
  proj_gemm2<<<2304, 512, 0, stream>>>(xb, wpb, bp, out);
}